// Round 5
// baseline (6234.420 us; speedup 1.0000x reference)
//
#include <hip/hip_runtime.h>

// LSTM LM forward on gfx950.
// R5 design (delta vs R4):
//  - Epoch-TAGGED H exchange: unit is a u64 {hi = step tag, lo = 2xbf16 H pair}
//    moved with single relaxed AGENT-scope 64-bit atomics. Tag+data arrive
//    together (single-copy atomic) -> NO flags, NO fences, NO poller wave, NO
//    store drain on the critical path. Each consumer thread polls exactly the
//    16 u64s it needs (all from one peer wave) and retries stragglers.
//  - Loop now has only TWO __syncthreads (LDS tile publish / yred publish).
//  - Double-buffer safety is transitive through the tags: overwriting parity p
//    at step s+2 requires the whole group to have consumed parity p at step s.
// Carried from R4: 4 independent batch groups x 32 WGs, weights persistent in
// VGPRs (20 A-frags), MFMA 16x16x32 bf16, lane acc = {i,f,o,c} for one (b,h),
// folded output head Y = H.v + c0, x tiles double-buffered in LDS.

typedef short bf16x8 __attribute__((ext_vector_type(8)));
typedef float f32x4  __attribute__((ext_vector_type(4)));
typedef unsigned short ushort_t;
typedef unsigned long long u64;

#define S_LEN 1024
#define NB    64
#define NH    512
#define NE    128
#define NGRP  4
#define NWPG  32              // WGs per group
#define NWGT  (NGRP * NWPG)   // 128 total

// workspace byte offsets
#define OFF_WPACK 0UL                          // 128*20*64*16 = 2,621,440
#define OFF_XBF   2621440UL                    // 1024*64*128*2 = 16,777,216
#define OFF_EXCH  19398656UL                   // 4 grp * 2 par * 4096 u64 * 8 = 262,144
#define OFF_V     19660800UL                   // 512*4
#define OFF_C0S   19662848UL                   // 16
#define OFF_YPART 19663360UL                   // 1024*128*16*4 = 8,388,608

__device__ __forceinline__ ushort_t f2bf(float f){
    union { float f; unsigned u; } v; v.f = f;
    unsigned u = v.u;
    unsigned r = (u + 0x7fffu + ((u >> 16) & 1u)) >> 16;
    return (ushort_t)r;
}
__device__ __forceinline__ float sigm(float x){ return 1.f / (1.f + __expf(-x)); }
__device__ __forceinline__ float tanh_(float x){ float e = __expf(2.f * x); return (e - 1.f) / (e + 1.f); }

// ---- prep: pack W into MFMA A-operand fragments (bf16) ----------------------
// wpack[q][ks][lane][j]: A[m=lane&15][k=32*ks+(lane>>4)*8+j]; m -> h=4q+(m>>2),
// gate g=m&3; k<512: W_h[g][k][h]; k>=512: W_x[g][k-512][h]
__global__ void pack_weights(const float* __restrict__ Wxi, const float* __restrict__ Whi,
                             const float* __restrict__ Wxf, const float* __restrict__ Whf,
                             const float* __restrict__ Wxo, const float* __restrict__ Who,
                             const float* __restrict__ Wxc, const float* __restrict__ Whc,
                             ushort_t* __restrict__ wpack){
    int bid = blockIdx.x;            // = q*20 + ks
    int q = bid / 20, ks = bid % 20;
    int l = threadIdx.x;             // 0..63
    int m = l & 15, quad = l >> 4;
    int h = q * 4 + (m >> 2), g = m & 3;
    const float* Wh = (g == 0) ? Whi : (g == 1) ? Whf : (g == 2) ? Who : Whc;
    const float* Wx = (g == 0) ? Wxi : (g == 1) ? Wxf : (g == 2) ? Wxo : Wxc;
    union { ushort_t u[8]; uint4 v4; } tmp;
    #pragma unroll
    for (int j = 0; j < 8; j++){
        int k = ks * 32 + quad * 8 + j;
        float w = (k < NH) ? Wh[(size_t)k * NH + h] : Wx[(size_t)(k - NH) * NH + h];
        tmp.u[j] = f2bf(w);
    }
    *(uint4*)(wpack + ((size_t)bid * 64 + l) * 8) = tmp.v4;
}

// ---- prep: bf16 embeddings, layout [s][b][e] --------------------------------
__global__ void prep_x(const int* __restrict__ inputs, const float* __restrict__ emb,
                       ushort_t* __restrict__ xbf){
    unsigned tid = blockIdx.x * 256u + threadIdx.x;   // = (s*64+b)*128 + e
    unsigned e = tid & 127u;
    unsigned b = (tid >> 7) & 63u;
    unsigned s = tid >> 13;
    int row = inputs[(size_t)b * S_LEN + s];
    xbf[tid] = f2bf(emb[(size_t)row * NE + e]);
}

// ---- prep: v = W_hq @ dense_w, c0, exch init (H0, tag 0, parity 0) ----------
__global__ void prep_v(const float* __restrict__ Whq, const float* __restrict__ bq,
                       const float* __restrict__ dw, const float* __restrict__ db,
                       const float* __restrict__ H0, float* __restrict__ v,
                       float* __restrict__ c0, u64* __restrict__ exch){
    int t = threadIdx.x;   // 512 threads, 1 block
    float a = 0.f;
    for (int e = 0; e < NE; e++) a += Whq[(size_t)t * NE + e] * dw[e];
    v[t] = a;
    if (t == 0){
        float c = db[0];
        for (int e = 0; e < NE; e++) c += bq[e] * dw[e];
        *c0 = c;
    }
    // exch layout: [grp][parity][16 b_local][256 hpair] of u64 {tag, data}
    int p = t & 255, half = t >> 8;
    for (int b = half * 32; b < half * 32 + 32; b++){
        unsigned lo = (unsigned)f2bf(H0[(size_t)b * NH + 2 * p]) |
                      ((unsigned)f2bf(H0[(size_t)b * NH + 2 * p + 1]) << 16);
        exch[(size_t)(b >> 4) * 8192 + (size_t)(b & 15) * 256 + p] = (u64)lo;  // hi=tag=0
    }
}

// ---- final: Y[s,b] = c0 + sum_wgin ypart[s][grp(b)][wgin][b&15] -------------
__global__ void reduce_y(const float* __restrict__ ypart, const float* __restrict__ c0,
                         float* __restrict__ dout){
    int t = blockIdx.x * 256 + threadIdx.x;   // t = s*64 + b, 65536 total
    int s = t >> 6, b = t & 63;
    int g = b >> 4, bl = b & 15;
    float a = *c0;
    const float* base = ypart + (((size_t)s * NGRP + g) * NWPG) * 16 + bl;
    #pragma unroll 4
    for (int w = 0; w < NWPG; w++) a += base[w * 16];
    dout[t] = a;
}

// ---- the recurrence ---------------------------------------------------------
__launch_bounds__(256, 1)
__global__ void lstm_coop(const float* __restrict__ C0,
                          const float* __restrict__ b_i, const float* __restrict__ b_f,
                          const float* __restrict__ b_o, const float* __restrict__ b_c,
                          const ushort_t* __restrict__ wpack, const ushort_t* __restrict__ xbf,
                          u64* __restrict__ exch, const float* __restrict__ v,
                          float* __restrict__ ypart, float* __restrict__ dout){
    // LDS: H tile [16 rows][65 uint4] (+1 uint4 pad -> dword stride 260,
    // conflict-free b32 staging writes), x tile double-buffered [2][16][17]
    // uint4, y reduction [4][16]
    __shared__ uint4 Hs[16][65];
    __shared__ uint4 Xs[2][16][17];
    __shared__ float yred[4][16];

    const int tid  = threadIdx.x;
    const int lane = tid & 63;
    const int wv   = tid >> 6;
    const int wg   = blockIdx.x;
    const int g    = wg >> 5;              // batch group 0..3
    const int wgin = wg & 31;              // WG index within group
    const int q    = wgin * 4 + wv;        // h-slot 0..127
    const int quad = lane >> 4;
    const int col  = lane & 15;
    const int h    = q * 4 + quad;         // this lane's h column
    const int b    = g * 16 + col;         // this lane's batch

    // persistent weights: 20 A-fragments (K=640)
    bf16x8 wfrag[20];
    #pragma unroll
    for (int ks = 0; ks < 20; ks++)
        wfrag[ks] = *(const bf16x8*)(wpack + ((size_t)(q * 20 + ks) * 64 + lane) * 8);

    const float bias0 = b_i[h], bias1 = b_f[h], bias2 = b_o[h], bias3 = b_c[h];
    const float vv = v[h];
    float C = C0[(size_t)b * NH + h];

    u64* exg = exch + (size_t)g * 8192;    // this group's double buffer

    const char* HsB = (const char*)Hs;
    const char* XsB = (const char*)Xs;
    unsigned* HsD = (unsigned*)Hs;

    // preload x tile for s=0 into Xs[0]
    {
        const uint4* x0 = (const uint4*)(xbf + (size_t)(g * 16) * NE);
        Xs[0][tid >> 4][tid & 15] = x0[tid];
    }

    for (int s = 0; s < S_LEN; s++){
        // issue x prefetch for s+1 (lands during poll/MFMA)
        int sn = (s + 1 < S_LEN) ? s + 1 : s;
        uint4 xr = ((const uint4*)(xbf + ((size_t)sn * NB + g * 16) * NE))[tid];

        // ---- poll tagged H(s): 16 u64 per thread, all from one peer wave -----
        {
            const u64* ex = exg + (size_t)(s & 1) * 4096;
            const unsigned tag = (unsigned)s;
            u64 hv[16];
            #pragma unroll
            for (int j = 0; j < 16; j++)
                hv[j] = __hip_atomic_load(ex + (size_t)j * 256 + tid, __ATOMIC_RELAXED,
                                          __HIP_MEMORY_SCOPE_AGENT);
            #pragma unroll
            for (int j = 0; j < 16; j++){
                while ((unsigned)(hv[j] >> 32) != tag){
                    __builtin_amdgcn_s_sleep(1);
                    hv[j] = __hip_atomic_load(ex + (size_t)j * 256 + tid, __ATOMIC_RELAXED,
                                              __HIP_MEMORY_SCOPE_AGENT);
                }
            }
            #pragma unroll
            for (int j = 0; j < 16; j++)
                HsD[j * 260 + tid] = (unsigned)hv[j];   // b_local=j, dword tid
        }
        Xs[(s + 1) & 1][tid >> 4][tid & 15] = xr;
        __syncthreads();   // S1: Hs + Xs ready

        // ---- 20 MFMA from LDS -------------------------------------------------
        f32x4 acc = (f32x4){0.f, 0.f, 0.f, 0.f};
        #pragma unroll
        for (int ks = 0; ks < 16; ks++){
            bf16x8 bfr = *(const bf16x8*)(HsB + col * 1040 + ks * 64 + quad * 16);
            acc = __builtin_amdgcn_mfma_f32_16x16x32_bf16(wfrag[ks], bfr, acc, 0, 0, 0);
        }
        #pragma unroll
        for (int kx = 0; kx < 4; kx++){
            bf16x8 bfr = *(const bf16x8*)(XsB + (s & 1) * 4352 + col * 272 + kx * 64 + quad * 16);
            acc = __builtin_amdgcn_mfma_f32_16x16x32_bf16(wfrag[16 + kx], bfr, acc, 0, 0, 0);
        }

        // ---- cell update: acc regs = {i,f,o,c} for (b, h) ---------------------
        float I = sigm(acc[0] + bias0);
        float F = sigm(acc[1] + bias1);
        float O = sigm(acc[2] + bias2);
        float G = tanh_(acc[3] + bias3);
        float Cn = F * C + I * G;
        float Hn = O * tanh_(Cn);
        C = Cn;

        // ---- publish H(s+1): tagged u64, lane-pair packed, fire-and-forget ----
        {
            float Hn_hi = __shfl_xor(Hn, 16, 64);     // partner quad's value
            unsigned lo = (unsigned)f2bf(Hn) | ((unsigned)f2bf(Hn_hi) << 16);
            if ((quad & 1) == 0 && s < S_LEN - 1){
                u64* ew = exg + (size_t)((s + 1) & 1) * 4096;
                unsigned idx = (unsigned)col * 256 + (unsigned)(q * 2) + (unsigned)(quad >> 1);
                u64 word = ((u64)(unsigned)(s + 1) << 32) | (u64)lo;
                __hip_atomic_store(ew + idx, word, __ATOMIC_RELAXED,
                                   __HIP_MEMORY_SCOPE_AGENT);
            }
        }

        float p = Hn * vv;                        // Y partial: sum this wave's 4 h
        p += __shfl_xor(p, 16, 64);
        p += __shfl_xor(p, 32, 64);
        if (quad == 0) yred[wv][col] = p;
        if (s == S_LEN - 1){
            dout[65536 + (size_t)b * NH + h] = Hn;   // final H
            dout[98304 + (size_t)b * NH + h] = Cn;   // final C
        }
        __syncthreads();   // S2: yred published
        if (tid < 16)
            ypart[(((size_t)s * NGRP + g) * NWPG + wgin) * 16 + tid] =
                yred[0][tid] + yred[1][tid] + yred[2][tid] + yred[3][tid];
        // no further barrier: step s+1's LDS writes happen after this S2, and
        // yred reads above complete before their readers reach S1 of s+1.
    }
}

extern "C" void kernel_launch(void* const* d_in, const int* in_sizes, int n_in,
                              void* d_out, int out_size, void* d_ws, size_t ws_size,
                              hipStream_t stream){
    const int*   inputs = (const int*)  d_in[0];
    const float* H0     = (const float*)d_in[1];
    const float* C0     = (const float*)d_in[2];
    const float* emb    = (const float*)d_in[3];
    const float* W_xi   = (const float*)d_in[4];
    const float* W_hi   = (const float*)d_in[5];
    const float* b_i    = (const float*)d_in[6];
    const float* W_xf   = (const float*)d_in[7];
    const float* W_hf   = (const float*)d_in[8];
    const float* b_f    = (const float*)d_in[9];
    const float* W_xo   = (const float*)d_in[10];
    const float* W_ho   = (const float*)d_in[11];
    const float* b_o    = (const float*)d_in[12];
    const float* W_xc   = (const float*)d_in[13];
    const float* W_hc   = (const float*)d_in[14];
    const float* b_c    = (const float*)d_in[15];
    const float* W_hq   = (const float*)d_in[16];
    const float* b_q    = (const float*)d_in[17];
    const float* dw     = (const float*)d_in[18];
    const float* db     = (const float*)d_in[19];
    float* dout = (float*)d_out;

    char* ws = (char*)d_ws;
    ushort_t* wpack = (ushort_t*)(ws + OFF_WPACK);
    ushort_t* xbf   = (ushort_t*)(ws + OFF_XBF);
    u64*      exch  = (u64*)     (ws + OFF_EXCH);
    float*    v     = (float*)   (ws + OFF_V);
    float*    c0    = (float*)   (ws + OFF_C0S);
    float*    ypart = (float*)   (ws + OFF_YPART);

    pack_weights<<<dim3(128 * 20), dim3(64), 0, stream>>>(W_xi, W_hi, W_xf, W_hf,
                                                          W_xo, W_ho, W_xc, W_hc, wpack);
    prep_x<<<dim3((S_LEN * NB * NE) / 256), dim3(256), 0, stream>>>(inputs, emb, xbf);
    prep_v<<<dim3(1), dim3(512), 0, stream>>>(W_hq, b_q, dw, db, H0, v, c0, exch);

    void* args[] = { (void*)&C0, (void*)&b_i, (void*)&b_f, (void*)&b_o, (void*)&b_c,
                     (void*)&wpack, (void*)&xbf, (void*)&exch, (void*)&v,
                     (void*)&ypart, (void*)&dout };
    hipLaunchCooperativeKernel((void*)lstm_coop, dim3(NWGT), dim3(256), args, 0, stream);

    reduce_y<<<dim3(65536 / 256), dim3(256), 0, stream>>>(ypart, c0, dout);
}

// Round 6
// 4082.721 us; speedup vs baseline: 1.5270x; 1.5270x over previous
//
#include <hip/hip_runtime.h>

// LSTM LM forward on gfx950.
// R6 design (delta vs R5):
//  - Batched masked re-poll: initial 16 pipelined u64 loads; retry sweeps
//    reload ALL still-stale words at once (bitmask) -> 1 LIC RTT per sweep
//    instead of R5's up-to-16 serialized dependent retries. Structure forces
//    all 16 u64s live at the check -> compiler must pipeline (VGPR up, wanted).
//  - ONE __syncthreads per step: Hs double-buffered, Xs triple-buffered (mod 3)
//    so the s+1 prefetch write can never race the s MFMA reads.
//  - Y epilogue off the critical path: 2 shfls + 16 fire-and-forget
//    unsafeAtomicAdd (HW fadd) per wave onto dout (pre-init to c0). No ypart,
//    no reduce kernel, no second barrier.
// Carried: tagged u64 {step, 2xbf16} H exchange via relaxed AGENT-scope
// atomics (no fences/flags), 4 batch groups x 32 WGs, weights persistent in
// VGPRs (20 A-frags), MFMA 16x16x32 bf16, folded head Y = H.v + c0.

typedef short bf16x8 __attribute__((ext_vector_type(8)));
typedef float f32x4  __attribute__((ext_vector_type(4)));
typedef unsigned short ushort_t;
typedef unsigned long long u64;

#define S_LEN 1024
#define NB    64
#define NH    512
#define NE    128
#define NGRP  4
#define NWPG  32              // WGs per group
#define NWGT  (NGRP * NWPG)   // 128 total

// workspace byte offsets
#define OFF_WPACK 0UL                          // 128*20*64*16 = 2,621,440
#define OFF_XBF   2621440UL                    // 1024*64*128*2 = 16,777,216
#define OFF_EXCH  19398656UL                   // 4 grp * 2 par * 4096 u64 * 8 = 262,144
#define OFF_V     19660800UL                   // 512*4
#define OFF_C0S   19662848UL                   // 16

__device__ __forceinline__ ushort_t f2bf(float f){
    union { float f; unsigned u; } v; v.f = f;
    unsigned u = v.u;
    unsigned r = (u + 0x7fffu + ((u >> 16) & 1u)) >> 16;
    return (ushort_t)r;
}
__device__ __forceinline__ float sigm(float x){ return 1.f / (1.f + __expf(-x)); }
__device__ __forceinline__ float tanh_(float x){ float e = __expf(2.f * x); return (e - 1.f) / (e + 1.f); }

// ---- prep: pack W into MFMA A-operand fragments (bf16) ----------------------
// wpack[q][ks][lane][j]: A[m=lane&15][k=32*ks+(lane>>4)*8+j]; m -> h=4q+(m>>2),
// gate g=m&3; k<512: W_h[g][k][h]; k>=512: W_x[g][k-512][h]
__global__ void pack_weights(const float* __restrict__ Wxi, const float* __restrict__ Whi,
                             const float* __restrict__ Wxf, const float* __restrict__ Whf,
                             const float* __restrict__ Wxo, const float* __restrict__ Who,
                             const float* __restrict__ Wxc, const float* __restrict__ Whc,
                             ushort_t* __restrict__ wpack){
    int bid = blockIdx.x;            // = q*20 + ks
    int q = bid / 20, ks = bid % 20;
    int l = threadIdx.x;             // 0..63
    int m = l & 15, quad = l >> 4;
    int h = q * 4 + (m >> 2), g = m & 3;
    const float* Wh = (g == 0) ? Whi : (g == 1) ? Whf : (g == 2) ? Who : Whc;
    const float* Wx = (g == 0) ? Wxi : (g == 1) ? Wxf : (g == 2) ? Wxo : Wxc;
    union { ushort_t u[8]; uint4 v4; } tmp;
    #pragma unroll
    for (int j = 0; j < 8; j++){
        int k = ks * 32 + quad * 8 + j;
        float w = (k < NH) ? Wh[(size_t)k * NH + h] : Wx[(size_t)(k - NH) * NH + h];
        tmp.u[j] = f2bf(w);
    }
    *(uint4*)(wpack + ((size_t)bid * 64 + l) * 8) = tmp.v4;
}

// ---- prep: bf16 embeddings, layout [s][b][e] --------------------------------
__global__ void prep_x(const int* __restrict__ inputs, const float* __restrict__ emb,
                       ushort_t* __restrict__ xbf){
    unsigned tid = blockIdx.x * 256u + threadIdx.x;   // = (s*64+b)*128 + e
    unsigned e = tid & 127u;
    unsigned b = (tid >> 7) & 63u;
    unsigned s = tid >> 13;
    int row = inputs[(size_t)b * S_LEN + s];
    xbf[tid] = f2bf(emb[(size_t)row * NE + e]);
}

// ---- prep: v = W_hq @ dense_w, c0, exch init (H0, tag 0, parity 0) ----------
__global__ void prep_v(const float* __restrict__ Whq, const float* __restrict__ bq,
                       const float* __restrict__ dw, const float* __restrict__ db,
                       const float* __restrict__ H0, float* __restrict__ v,
                       float* __restrict__ c0, u64* __restrict__ exch){
    int t = threadIdx.x;   // 512 threads, 1 block
    float a = 0.f;
    for (int e = 0; e < NE; e++) a += Whq[(size_t)t * NE + e] * dw[e];
    v[t] = a;
    if (t == 0){
        float c = db[0];
        for (int e = 0; e < NE; e++) c += bq[e] * dw[e];
        *c0 = c;
    }
    // exch layout: [grp][parity][16 b_local][256 hpair] of u64 {tag, data}
    int p = t & 255, half = t >> 8;
    for (int b = half * 32; b < half * 32 + 32; b++){
        unsigned lo = (unsigned)f2bf(H0[(size_t)b * NH + 2 * p]) |
                      ((unsigned)f2bf(H0[(size_t)b * NH + 2 * p + 1]) << 16);
        exch[(size_t)(b >> 4) * 8192 + (size_t)(b & 15) * 256 + p] = (u64)lo;  // hi=tag=0
    }
}

// ---- prep: init Y region of d_out to c0 (waves fadd onto it) ----------------
__global__ void init_y(const float* __restrict__ c0, float* __restrict__ dout){
    int tid = blockIdx.x * 256 + threadIdx.x;   // 65536 = S*B
    dout[tid] = *c0;
}

// ---- the recurrence ---------------------------------------------------------
__launch_bounds__(256, 1)
__global__ void lstm_coop(const float* __restrict__ C0,
                          const float* __restrict__ b_i, const float* __restrict__ b_f,
                          const float* __restrict__ b_o, const float* __restrict__ b_c,
                          const ushort_t* __restrict__ wpack, const ushort_t* __restrict__ xbf,
                          u64* __restrict__ exch, const float* __restrict__ v,
                          float* __restrict__ dout){
    // LDS: Hs double-buffered [2][16 rows][65 uint4] (+1 uint4 pad -> dword
    // stride 260, conflict-free staging), Xs triple-buffered [3][16][17] uint4.
    __shared__ uint4 Hs[2][16][65];
    __shared__ uint4 Xs[3][16][17];

    const int tid  = threadIdx.x;
    const int lane = tid & 63;
    const int wv   = tid >> 6;
    const int wg   = blockIdx.x;
    const int g    = wg >> 5;              // batch group 0..3
    const int wgin = wg & 31;              // WG index within group
    const int q    = wgin * 4 + wv;        // h-slot 0..127
    const int quad = lane >> 4;
    const int col  = lane & 15;
    const int h    = q * 4 + quad;         // this lane's h column
    const int b    = g * 16 + col;         // this lane's batch

    // persistent weights: 20 A-fragments (K=640)
    bf16x8 wfrag[20];
    #pragma unroll
    for (int ks = 0; ks < 20; ks++)
        wfrag[ks] = *(const bf16x8*)(wpack + ((size_t)(q * 20 + ks) * 64 + lane) * 8);

    const float bias0 = b_i[h], bias1 = b_f[h], bias2 = b_o[h], bias3 = b_c[h];
    const float vv = v[h];
    float C = C0[(size_t)b * NH + h];

    u64* exg = exch + (size_t)g * 8192;    // this group's double buffer

    const char* HsB = (const char*)Hs;
    const char* XsB = (const char*)Xs;
    unsigned* HsD = (unsigned*)Hs;

    // preload x tile for s=0 into Xs[0]
    {
        const uint4* x0 = (const uint4*)(xbf + (size_t)(g * 16) * NE);
        Xs[0][tid >> 4][tid & 15] = x0[tid];
    }

    for (int s = 0; s < S_LEN; s++){
        // issue x prefetch for s+1 (lands during poll)
        int sn = (s + 1 < S_LEN) ? s + 1 : s;
        uint4 xr = ((const uint4*)(xbf + ((size_t)sn * NB + g * 16) * NE))[tid];

        // ---- poll tagged H(s): 16 pipelined u64 loads + batched masked retry --
        {
            const u64* ex = exg + (size_t)(s & 1) * 4096;
            const unsigned tag = (unsigned)s;
            u64 hv[16];
            #pragma unroll
            for (int j = 0; j < 16; j++)
                hv[j] = __hip_atomic_load(ex + (size_t)j * 256 + tid, __ATOMIC_RELAXED,
                                          __HIP_MEMORY_SCOPE_AGENT);
            unsigned pend = 0;
            #pragma unroll
            for (int j = 0; j < 16; j++)
                pend |= ((unsigned)(hv[j] >> 32) != tag) ? (1u << j) : 0u;
            while (__builtin_expect(pend != 0, 0)){
                __builtin_amdgcn_s_sleep(1);
                #pragma unroll
                for (int j = 0; j < 16; j++)
                    if (pend & (1u << j))
                        hv[j] = __hip_atomic_load(ex + (size_t)j * 256 + tid, __ATOMIC_RELAXED,
                                                  __HIP_MEMORY_SCOPE_AGENT);
                unsigned np = 0;
                #pragma unroll
                for (int j = 0; j < 16; j++)
                    np |= ((unsigned)(hv[j] >> 32) != tag) ? (1u << j) : 0u;
                pend = np;
            }
            #pragma unroll
            for (int j = 0; j < 16; j++)
                HsD[(s & 1) * 4160 + j * 260 + tid] = (unsigned)hv[j];  // row j, dword tid
        }
        Xs[(s + 1) % 3][tid >> 4][tid & 15] = xr;
        __syncthreads();   // S1 (the only barrier): Hs[s&1] + Xs[s%3] ready

        // ---- 20 MFMA from LDS -------------------------------------------------
        f32x4 acc = (f32x4){0.f, 0.f, 0.f, 0.f};
        #pragma unroll
        for (int ks = 0; ks < 16; ks++){
            bf16x8 bfr = *(const bf16x8*)(HsB + (s & 1) * 16640 + col * 1040 + ks * 64 + quad * 16);
            acc = __builtin_amdgcn_mfma_f32_16x16x32_bf16(wfrag[ks], bfr, acc, 0, 0, 0);
        }
        #pragma unroll
        for (int kx = 0; kx < 4; kx++){
            bf16x8 bfr = *(const bf16x8*)(XsB + (s % 3) * 4352 + col * 272 + kx * 64 + quad * 16);
            acc = __builtin_amdgcn_mfma_f32_16x16x32_bf16(wfrag[16 + kx], bfr, acc, 0, 0, 0);
        }

        // ---- cell update: acc regs = {i,f,o,c} for (b, h) ---------------------
        float I = sigm(acc[0] + bias0);
        float F = sigm(acc[1] + bias1);
        float O = sigm(acc[2] + bias2);
        float G = tanh_(acc[3] + bias3);
        float Cn = F * C + I * G;
        float Hn = O * tanh_(Cn);
        C = Cn;

        // ---- publish H(s+1) ASAP: tagged u64, lane-pair packed ---------------
        float Hn_hi = __shfl_xor(Hn, 16, 64);         // partner quad's value
        {
            unsigned lo = (unsigned)f2bf(Hn) | ((unsigned)f2bf(Hn_hi) << 16);
            if ((quad & 1) == 0 && s < S_LEN - 1){
                u64* ew = exg + (size_t)((s + 1) & 1) * 4096;
                unsigned idx = (unsigned)col * 256 + (unsigned)(q * 2) + (unsigned)(quad >> 1);
                u64 word = ((u64)(unsigned)(s + 1) << 32) | (u64)lo;
                __hip_atomic_store(ew + idx, word, __ATOMIC_RELAXED,
                                   __HIP_MEMORY_SCOPE_AGENT);
            }
        }

        // ---- Y: fire-and-forget HW fadd (no barrier, no spill buffer) ---------
        float p = Hn * vv;
        p += __shfl_xor(p, 16, 64);
        p += __shfl_xor(p, 32, 64);
        if (quad == 0)
            unsafeAtomicAdd(&dout[(size_t)s * NB + b], p);

        if (s == S_LEN - 1){
            dout[65536 + (size_t)b * NH + h] = Hn;   // final H
            dout[98304 + (size_t)b * NH + h] = Cn;   // final C
        }
    }
}

extern "C" void kernel_launch(void* const* d_in, const int* in_sizes, int n_in,
                              void* d_out, int out_size, void* d_ws, size_t ws_size,
                              hipStream_t stream){
    const int*   inputs = (const int*)  d_in[0];
    const float* H0     = (const float*)d_in[1];
    const float* C0     = (const float*)d_in[2];
    const float* emb    = (const float*)d_in[3];
    const float* W_xi   = (const float*)d_in[4];
    const float* W_hi   = (const float*)d_in[5];
    const float* b_i    = (const float*)d_in[6];
    const float* W_xf   = (const float*)d_in[7];
    const float* W_hf   = (const float*)d_in[8];
    const float* b_f    = (const float*)d_in[9];
    const float* W_xo   = (const float*)d_in[10];
    const float* W_ho   = (const float*)d_in[11];
    const float* b_o    = (const float*)d_in[12];
    const float* W_xc   = (const float*)d_in[13];
    const float* W_hc   = (const float*)d_in[14];
    const float* b_c    = (const float*)d_in[15];
    const float* W_hq   = (const float*)d_in[16];
    const float* b_q    = (const float*)d_in[17];
    const float* dw     = (const float*)d_in[18];
    const float* db     = (const float*)d_in[19];
    float* dout = (float*)d_out;

    char* ws = (char*)d_ws;
    ushort_t* wpack = (ushort_t*)(ws + OFF_WPACK);
    ushort_t* xbf   = (ushort_t*)(ws + OFF_XBF);
    u64*      exch  = (u64*)     (ws + OFF_EXCH);
    float*    v     = (float*)   (ws + OFF_V);
    float*    c0    = (float*)   (ws + OFF_C0S);

    pack_weights<<<dim3(128 * 20), dim3(64), 0, stream>>>(W_xi, W_hi, W_xf, W_hf,
                                                          W_xo, W_ho, W_xc, W_hc, wpack);
    prep_x<<<dim3((S_LEN * NB * NE) / 256), dim3(256), 0, stream>>>(inputs, emb, xbf);
    prep_v<<<dim3(1), dim3(512), 0, stream>>>(W_hq, b_q, dw, db, H0, v, c0, exch);
    init_y<<<dim3(65536 / 256), dim3(256), 0, stream>>>(c0, dout);

    void* args[] = { (void*)&C0, (void*)&b_i, (void*)&b_f, (void*)&b_o, (void*)&b_c,
                     (void*)&wpack, (void*)&xbf, (void*)&exch, (void*)&v, (void*)&dout };
    hipLaunchCooperativeKernel((void*)lstm_coop, dim3(NWGT), dim3(256), args, 0, stream);
}

// Round 10
// 3117.474 us; speedup vs baseline: 1.9998x; 1.3096x over previous
//
#include <hip/hip_runtime.h>

// LSTM LM forward on gfx950.
// R10 = R6's launch-proven kernel (128 WGs, 4 groups x 32 WGs x 16 batches,
// 1 h-slot/wave, wfrag[20]) + three minimal deltas:
//  1. Y epilogue: NO atomics. Wave partial -> yred LDS (parity dbuf) ->
//     deferred flush to ypart after the NEXT step's barrier -> reduce_y
//     kernel. (R6's 2048 same-line unsafeAtomicAdds/group/step retired
//     in-order through vmcnt => next step's poll loads queued behind them.)
//  2. x-part MFMAs issued BEFORE the poll resweep (Xs[s%3] was synced at
//     step s-1; pre-loop barrier covers s=0) -> overlaps the wait.
//  3. 2-way split accumulator on H-MFMAs (halves dependent chain).
// Carried from R6 (passed, 3.95ms): tagged u64 {step, 2xbf16} H exchange via
// relaxed AGENT-scope atomics, 16-word pipelined poll + reload-all resweep,
// one __syncthreads/step, Hs dbuf + Xs triple-buf, folded head Y = H.v + c0.

typedef short bf16x8 __attribute__((ext_vector_type(8)));
typedef float f32x4  __attribute__((ext_vector_type(4)));
typedef unsigned short ushort_t;
typedef unsigned long long u64;

#define S_LEN 1024
#define NB    64
#define NH    512
#define NE    128
#define NGRP  4
#define NWPG  32              // WGs per group
#define NWGT  128             // total WGs

// workspace byte offsets
#define OFF_WPACK 0UL                          // 128*20*64*16 = 2,621,440
#define OFF_XBF   2621440UL                    // 1024*64*128*2 = 16,777,216
#define OFF_EXCH  19398656UL                   // 4 grp * 2 par * 4096 u64 * 8 = 262,144
#define OFF_V     19660800UL                   // 512*4
#define OFF_C0S   19662848UL                   // 16
#define OFF_YPART 19663360UL                   // 1024*4*32*16*4 = 8,388,608

__device__ __forceinline__ ushort_t f2bf(float f){
    union { float f; unsigned u; } v; v.f = f;
    unsigned u = v.u;
    unsigned r = (u + 0x7fffu + ((u >> 16) & 1u)) >> 16;
    return (ushort_t)r;
}
__device__ __forceinline__ float sigm(float x){ return 1.f / (1.f + __expf(-x)); }
__device__ __forceinline__ float tanh_(float x){ float e = __expf(2.f * x); return (e - 1.f) / (e + 1.f); }

// ---- prep: pack W into MFMA A-operand fragments (bf16) ----------------------
// wpack[q][ks][lane][j]: A[m=lane&15][k=32*ks+(lane>>4)*8+j]; m -> h=4q+(m>>2),
// gate g=m&3; k<512: W_h[g][k][h]; k>=512: W_x[g][k-512][h]
__global__ void pack_weights(const float* __restrict__ Wxi, const float* __restrict__ Whi,
                             const float* __restrict__ Wxf, const float* __restrict__ Whf,
                             const float* __restrict__ Wxo, const float* __restrict__ Who,
                             const float* __restrict__ Wxc, const float* __restrict__ Whc,
                             ushort_t* __restrict__ wpack){
    int bid = blockIdx.x;            // = q*20 + ks
    int q = bid / 20, ks = bid % 20;
    int l = threadIdx.x;             // 0..63
    int m = l & 15, quad = l >> 4;
    int h = q * 4 + (m >> 2), g = m & 3;
    const float* Wh = (g == 0) ? Whi : (g == 1) ? Whf : (g == 2) ? Who : Whc;
    const float* Wx = (g == 0) ? Wxi : (g == 1) ? Wxf : (g == 2) ? Wxo : Wxc;
    union { ushort_t u[8]; uint4 v4; } tmp;
    #pragma unroll
    for (int j = 0; j < 8; j++){
        int k = ks * 32 + quad * 8 + j;
        float w = (k < NH) ? Wh[(size_t)k * NH + h] : Wx[(size_t)(k - NH) * NH + h];
        tmp.u[j] = f2bf(w);
    }
    *(uint4*)(wpack + ((size_t)bid * 64 + l) * 8) = tmp.v4;
}

// ---- prep: bf16 embeddings, layout [s][b][e] --------------------------------
__global__ void prep_x(const int* __restrict__ inputs, const float* __restrict__ emb,
                       ushort_t* __restrict__ xbf){
    unsigned tid = blockIdx.x * 256u + threadIdx.x;   // = (s*64+b)*128 + e
    unsigned e = tid & 127u;
    unsigned b = (tid >> 7) & 63u;
    unsigned s = tid >> 13;
    int row = inputs[(size_t)b * S_LEN + s];
    xbf[tid] = f2bf(emb[(size_t)row * NE + e]);
}

// ---- prep: v = W_hq @ dense_w, c0, exch init (H0, tag 0, parity 0) ----------
__global__ void prep_v(const float* __restrict__ Whq, const float* __restrict__ bq,
                       const float* __restrict__ dw, const float* __restrict__ db,
                       const float* __restrict__ H0, float* __restrict__ v,
                       float* __restrict__ c0, u64* __restrict__ exch){
    int t = threadIdx.x;   // 512 threads, 1 block
    float a = 0.f;
    for (int e = 0; e < NE; e++) a += Whq[(size_t)t * NE + e] * dw[e];
    v[t] = a;
    if (t == 0){
        float c = db[0];
        for (int e = 0; e < NE; e++) c += bq[e] * dw[e];
        *c0 = c;
    }
    // exch layout: [grp][parity][16 b_local][256 hpair] of u64 {tag, data}
    int p = t & 255, half = t >> 8;
    for (int b = half * 32; b < half * 32 + 32; b++){
        unsigned lo = (unsigned)f2bf(H0[(size_t)b * NH + 2 * p]) |
                      ((unsigned)f2bf(H0[(size_t)b * NH + 2 * p + 1]) << 16);
        exch[(size_t)(b >> 4) * 8192 + (size_t)(b & 15) * 256 + p] = (u64)lo;  // tag=0
    }
}

// ---- final: Y[s,b] = c0 + sum_wgin ypart[s][grp(b)][wgin][b&15] -------------
__global__ void reduce_y(const float* __restrict__ ypart, const float* __restrict__ c0,
                         float* __restrict__ dout){
    int t = blockIdx.x * 256 + threadIdx.x;   // t = s*64 + b, 65536 total
    int s = t >> 6, b = t & 63;
    int g = b >> 4, bl = b & 15;
    float a = *c0;
    const float* base = ypart + (((size_t)s * NGRP + g) * NWPG) * 16 + bl;
    #pragma unroll 4
    for (int w = 0; w < NWPG; w++) a += base[w * 16];
    dout[t] = a;
}

// ---- the recurrence ---------------------------------------------------------
__launch_bounds__(256, 1)
__global__ void lstm_coop(const float* __restrict__ C0,
                          const float* __restrict__ b_i, const float* __restrict__ b_f,
                          const float* __restrict__ b_o, const float* __restrict__ b_c,
                          const ushort_t* __restrict__ wpack, const ushort_t* __restrict__ xbf,
                          u64* __restrict__ exch, const float* __restrict__ v,
                          float* __restrict__ ypart, float* __restrict__ dout){
    // LDS: Hs double-buffered [2][16 rows][65 uint4] (+pad -> dword stride 260,
    // conflict-free staging), Xs triple-buffered [3][16][17] uint4,
    // yred parity-double-buffered wave partials.
    __shared__ uint4 Hs[2][16][65];
    __shared__ uint4 Xs[3][16][17];
    __shared__ float yred[2][4][16];

    const int tid  = threadIdx.x;
    const int lane = tid & 63;
    const int wv   = tid >> 6;
    const int wg   = blockIdx.x;
    const int g    = wg >> 5;              // batch group 0..3
    const int wgin = wg & 31;              // WG index within group
    const int q    = wgin * 4 + wv;        // h-slot 0..127
    const int quad = lane >> 4;
    const int col  = lane & 15;
    const int h    = q * 4 + quad;         // this lane's h column
    const int b    = g * 16 + col;         // this lane's batch

    // persistent weights: 20 A-fragments (K=640)
    bf16x8 wfrag[20];
    #pragma unroll
    for (int ks = 0; ks < 20; ks++)
        wfrag[ks] = *(const bf16x8*)(wpack + ((size_t)(q * 20 + ks) * 64 + lane) * 8);

    const float bias0 = b_i[h], bias1 = b_f[h], bias2 = b_o[h], bias3 = b_c[h];
    const float vv = v[h];
    float C = C0[(size_t)b * NH + h];

    u64* exg = exch + (size_t)g * 8192;    // this group's double buffer

    const char* HsB = (const char*)Hs;
    const char* XsB = (const char*)Xs;
    unsigned* HsD = (unsigned*)Hs;

    // preload x tile for s=0 into Xs[0]; barrier so early x-MFMAs at s=0 are safe
    {
        const uint4* x0 = (const uint4*)(xbf + (size_t)(g * 16) * NE);
        Xs[0][tid >> 4][tid & 15] = x0[tid];
    }
    __syncthreads();

    for (int s = 0; s < S_LEN; s++){
        // x prefetch for s+1 (lands during poll)
        int sn = (s + 1 < S_LEN) ? s + 1 : s;
        uint4 xr = ((const uint4*)(xbf + ((size_t)sn * NB + g * 16) * NE))[tid];

        // ---- issue poll loads for H(s) ---------------------------------------
        const u64* ex = exg + (size_t)(s & 1) * 4096;
        const unsigned tag = (unsigned)s;
        u64 hv[16];
        #pragma unroll
        for (int j = 0; j < 16; j++)
            hv[j] = __hip_atomic_load(ex + (size_t)j * 256 + tid, __ATOMIC_RELAXED,
                                      __HIP_MEMORY_SCOPE_AGENT);

        // ---- x-part MFMAs overlap the poll (Xs[s%3] synced at step s-1) ------
        f32x4 acc0 = (f32x4){0.f, 0.f, 0.f, 0.f};
        f32x4 acc1 = (f32x4){0.f, 0.f, 0.f, 0.f};
        #pragma unroll
        for (int kx = 0; kx < 4; kx++){
            bf16x8 bfr = *(const bf16x8*)(XsB + (s % 3) * 4352 + col * 272 + kx * 64 + quad * 16);
            if (kx & 1) acc1 = __builtin_amdgcn_mfma_f32_16x16x32_bf16(wfrag[16 + kx], bfr, acc1, 0, 0, 0);
            else        acc0 = __builtin_amdgcn_mfma_f32_16x16x32_bf16(wfrag[16 + kx], bfr, acc0, 0, 0, 0);
        }

        // ---- finish poll: reload-all resweep until every tag matches ---------
        for (;;){
            unsigned bad = 0;
            #pragma unroll
            for (int j = 0; j < 16; j++)
                bad |= ((unsigned)(hv[j] >> 32) != tag) ? 1u : 0u;
            if (!bad) break;
            __builtin_amdgcn_s_sleep(1);
            #pragma unroll
            for (int j = 0; j < 16; j++)
                hv[j] = __hip_atomic_load(ex + (size_t)j * 256 + tid, __ATOMIC_RELAXED,
                                          __HIP_MEMORY_SCOPE_AGENT);
        }
        #pragma unroll
        for (int j = 0; j < 16; j++)
            HsD[(s & 1) * 4160 + j * 260 + tid] = (unsigned)hv[j];  // row j, dword tid
        Xs[(s + 1) % 3][tid >> 4][tid & 15] = xr;
        __syncthreads();   // the only in-loop barrier: Hs[s&1] + Xs ready

        // ---- flush previous step's Y partials (reuses this barrier) ----------
        if (tid < 16 && s > 0)
            ypart[(((size_t)(s - 1) * NGRP + g) * NWPG + wgin) * 16 + tid] =
                yred[(s - 1) & 1][0][tid] + yred[(s - 1) & 1][1][tid] +
                yred[(s - 1) & 1][2][tid] + yred[(s - 1) & 1][3][tid];

        // ---- H-part: 16 MFMA from LDS (2-way split accumulator) --------------
        #pragma unroll
        for (int ks = 0; ks < 16; ks++){
            bf16x8 bfr = *(const bf16x8*)(HsB + (s & 1) * 16640 + col * 1040 + ks * 64 + quad * 16);
            if (ks & 1) acc1 = __builtin_amdgcn_mfma_f32_16x16x32_bf16(wfrag[ks], bfr, acc1, 0, 0, 0);
            else        acc0 = __builtin_amdgcn_mfma_f32_16x16x32_bf16(wfrag[ks], bfr, acc0, 0, 0, 0);
        }
        f32x4 acc = acc0 + acc1;

        // ---- cell update: acc regs = {i,f,o,c} for (b, h) ---------------------
        float I = sigm(acc[0] + bias0);
        float F = sigm(acc[1] + bias1);
        float O = sigm(acc[2] + bias2);
        float G = tanh_(acc[3] + bias3);
        float Cn = F * C + I * G;
        float Hn = O * tanh_(Cn);
        C = Cn;

        // ---- publish H(s+1): tagged u64, lane-pair packed, fire-and-forget ----
        float Hn_hi = __shfl_xor(Hn, 16, 64);         // partner quad's value
        {
            unsigned lo = (unsigned)f2bf(Hn) | ((unsigned)f2bf(Hn_hi) << 16);
            if ((quad & 1) == 0 && s < S_LEN - 1){
                u64* ew = exg + (size_t)((s + 1) & 1) * 4096;
                unsigned idx = (unsigned)col * 256 + (unsigned)(q * 2) + (unsigned)(quad >> 1);
                u64 word = ((u64)(unsigned)(s + 1) << 32) | (u64)lo;
                __hip_atomic_store(ew + idx, word, __ATOMIC_RELAXED,
                                   __HIP_MEMORY_SCOPE_AGENT);
            }
        }

        // ---- Y partial into LDS (read after NEXT step's barrier) -------------
        float p = Hn * vv;
        p += __shfl_xor(p, 16, 64);
        p += __shfl_xor(p, 32, 64);
        if (quad == 0) yred[s & 1][wv][col] = p;

        if (s == S_LEN - 1){
            dout[65536 + (size_t)b * NH + h] = Hn;   // final H
            dout[98304 + (size_t)b * NH + h] = Cn;   // final C
        }
    }
    // final Y flush for s = S_LEN-1
    __syncthreads();
    if (tid < 16)
        ypart[(((size_t)(S_LEN - 1) * NGRP + g) * NWPG + wgin) * 16 + tid] =
            yred[(S_LEN - 1) & 1][0][tid] + yred[(S_LEN - 1) & 1][1][tid] +
            yred[(S_LEN - 1) & 1][2][tid] + yred[(S_LEN - 1) & 1][3][tid];
}

extern "C" void kernel_launch(void* const* d_in, const int* in_sizes, int n_in,
                              void* d_out, int out_size, void* d_ws, size_t ws_size,
                              hipStream_t stream){
    const int*   inputs = (const int*)  d_in[0];
    const float* H0     = (const float*)d_in[1];
    const float* C0     = (const float*)d_in[2];
    const float* emb    = (const float*)d_in[3];
    const float* W_xi   = (const float*)d_in[4];
    const float* W_hi   = (const float*)d_in[5];
    const float* b_i    = (const float*)d_in[6];
    const float* W_xf   = (const float*)d_in[7];
    const float* W_hf   = (const float*)d_in[8];
    const float* b_f    = (const float*)d_in[9];
    const float* W_xo   = (const float*)d_in[10];
    const float* W_ho   = (const float*)d_in[11];
    const float* b_o    = (const float*)d_in[12];
    const float* W_xc   = (const float*)d_in[13];
    const float* W_hc   = (const float*)d_in[14];
    const float* b_c    = (const float*)d_in[15];
    const float* W_hq   = (const float*)d_in[16];
    const float* b_q    = (const float*)d_in[17];
    const float* dw     = (const float*)d_in[18];
    const float* db     = (const float*)d_in[19];
    float* dout = (float*)d_out;

    char* ws = (char*)d_ws;
    ushort_t* wpack = (ushort_t*)(ws + OFF_WPACK);
    ushort_t* xbf   = (ushort_t*)(ws + OFF_XBF);
    u64*      exch  = (u64*)     (ws + OFF_EXCH);
    float*    v     = (float*)   (ws + OFF_V);
    float*    c0    = (float*)   (ws + OFF_C0S);
    float*    ypart = (float*)   (ws + OFF_YPART);

    pack_weights<<<dim3(128 * 20), dim3(64), 0, stream>>>(W_xi, W_hi, W_xf, W_hf,
                                                          W_xo, W_ho, W_xc, W_hc, wpack);
    prep_x<<<dim3((S_LEN * NB * NE) / 256), dim3(256), 0, stream>>>(inputs, emb, xbf);
    prep_v<<<dim3(1), dim3(512), 0, stream>>>(W_hq, b_q, dw, db, H0, v, c0, exch);

    void* args[] = { (void*)&C0, (void*)&b_i, (void*)&b_f, (void*)&b_o, (void*)&b_c,
                     (void*)&wpack, (void*)&xbf, (void*)&exch, (void*)&v,
                     (void*)&ypart, (void*)&dout };
    hipLaunchCooperativeKernel((void*)lstm_coop, dim3(NWGT), dim3(256), args, 0, stream);

    reduce_y<<<dim3(65536 / 256), dim3(256), 0, stream>>>(ypart, c0, dout);
}